// Round 1
// baseline (1662.965 us; speedup 1.0000x reference)
//
#include <hip/hip_runtime.h>

#define NN 50000
#define NE 800000
#define DDIM 64
#define PADX 68          // padded LDS row stride (keeps 16B alignment, breaks pow2 banks)
#define NEG_SLOPE 0.2f
#define EPS_V 1e-5f

__device__ __forceinline__ float lrelu_f(float x) { return x >= 0.0f ? x : NEG_SLOPE * x; }

// acc[i*4+j] += sum_k XT[k][e0+i] * Wc[f0+j][k]
// XT: transposed activation tile [k][e], stride PADX
// Wc: row-major weight [f][k], stride PADX
__device__ __forceinline__ void mma_tile(float acc[16], const float* __restrict__ XT,
                                         const float* __restrict__ Wc, int e0, int f0)
{
    #pragma unroll 4
    for (int kk = 0; kk < DDIM; kk += 4) {
        float4 A0 = *(const float4*)&XT[(kk+0)*PADX + e0];
        float4 A1 = *(const float4*)&XT[(kk+1)*PADX + e0];
        float4 A2 = *(const float4*)&XT[(kk+2)*PADX + e0];
        float4 A3 = *(const float4*)&XT[(kk+3)*PADX + e0];
        float4 B0 = *(const float4*)&Wc[(f0+0)*PADX + kk];
        float4 B1 = *(const float4*)&Wc[(f0+1)*PADX + kk];
        float4 B2 = *(const float4*)&Wc[(f0+2)*PADX + kk];
        float4 B3 = *(const float4*)&Wc[(f0+3)*PADX + kk];
        const float a[4][4] = {{A0.x,A0.y,A0.z,A0.w},{A1.x,A1.y,A1.z,A1.w},
                               {A2.x,A2.y,A2.z,A2.w},{A3.x,A3.y,A3.z,A3.w}};
        const float b[4][4] = {{B0.x,B0.y,B0.z,B0.w},{B1.x,B1.y,B1.z,B1.w},
                               {B2.x,B2.y,B2.z,B2.w},{B3.x,B3.y,B3.z,B3.w}};
        #pragma unroll
        for (int j = 0; j < 4; ++j)
            #pragma unroll
            for (int i = 0; i < 4; ++i)
                #pragma unroll
                for (int q = 0; q < 4; ++q)
                    acc[i*4+j] = fmaf(a[q][i], b[j][q], acc[i*4+j]);
    }
}

// stage one 64x64 weight matrix (row-major [f][k]) into padded LDS
__device__ __forceinline__ void load_w(float* __restrict__ Wc, const float* __restrict__ Wg, int tid)
{
    #pragma unroll
    for (int c = 0; c < 4; ++c) {
        int idx = (c << 10) + (tid << 2);
        int f = idx >> 6, k = idx & 63;
        *(float4*)&Wc[f*PADX + k] = *(const float4*)&Wg[idx];
    }
}

// write acc (+bias, activation) back to XT as next layer's input: XT[f][e]
// ACT: 0 = none, 1 = relu, 2 = lrelu
template<int ACT>
__device__ __forceinline__ void store_act(float* __restrict__ XT, const float acc[16],
                                          const float4 bv, int e0, int f0)
{
    const float ba[4] = {bv.x, bv.y, bv.z, bv.w};
    #pragma unroll
    for (int j = 0; j < 4; ++j) {
        float t0 = acc[0*4+j] + ba[j];
        float t1 = acc[1*4+j] + ba[j];
        float t2 = acc[2*4+j] + ba[j];
        float t3 = acc[3*4+j] + ba[j];
        if (ACT == 1) { t0 = fmaxf(t0,0.f); t1 = fmaxf(t1,0.f); t2 = fmaxf(t2,0.f); t3 = fmaxf(t3,0.f); }
        if (ACT == 2) { t0 = lrelu_f(t0); t1 = lrelu_f(t1); t2 = lrelu_f(t2); t3 = lrelu_f(t3); }
        float4 v; v.x = t0; v.y = t1; v.z = t2; v.w = t3;
        *(float4*)&XT[(f0+j)*PADX + e0] = v;
    }
}

// ---------------- node pooling: Vp = lrelu(lrelu(V)@Aw^T + Ab) @ Bw^T + Bb ----------------
__global__ __launch_bounds__(256, 3)
void node_pool_kernel(const float* __restrict__ V,
                      const float* __restrict__ Aw, const float* __restrict__ Ab,
                      const float* __restrict__ Bw, const float* __restrict__ Bbv,
                      float* __restrict__ Vp)
{
    __shared__ float Wc[DDIM*PADX];
    __shared__ float XT[DDIM*PADX];
    const int tid = threadIdx.x;
    const int nb = blockIdx.x * 64;
    const int e0 = (tid & 15) << 2;
    const int f0 = (tid >> 4) << 2;

    #pragma unroll
    for (int c = 0; c < 4; ++c) {
        int idx = (c << 10) + (tid << 2);
        int e = idx >> 6, d = idx & 63;
        int row = nb + e; if (row > NN-1) row = NN-1;   // clamp tail; garbage rows not stored
        float4 v = *(const float4*)&V[(size_t)row*DDIM + d];
        XT[(d+0)*PADX + e] = lrelu_f(v.x);
        XT[(d+1)*PADX + e] = lrelu_f(v.y);
        XT[(d+2)*PADX + e] = lrelu_f(v.z);
        XT[(d+3)*PADX + e] = lrelu_f(v.w);
    }
    load_w(Wc, Aw, tid);
    __syncthreads();

    float acc[16];
    #pragma unroll
    for (int i = 0; i < 16; ++i) acc[i] = 0.f;
    mma_tile(acc, XT, Wc, e0, f0);
    __syncthreads();

    store_act<2>(XT, acc, *(const float4*)&Ab[f0], e0, f0);
    load_w(Wc, Bw, tid);
    __syncthreads();

    float acc2[16];
    #pragma unroll
    for (int i = 0; i < 16; ++i) acc2[i] = 0.f;
    mma_tile(acc2, XT, Wc, e0, f0);

    float4 bv = *(const float4*)&Bbv[f0];
    #pragma unroll
    for (int i = 0; i < 4; ++i) {
        int row = nb + e0 + i;
        if (row < NN) {
            float4 o;
            o.x = acc2[i*4+0] + bv.x;
            o.y = acc2[i*4+1] + bv.y;
            o.z = acc2[i*4+2] + bv.z;
            o.w = acc2[i*4+3] + bv.w;
            *(float4*)&Vp[(size_t)row*DDIM + f0] = o;
        }
    }
}

// ---------------- edge MLP + gated message + atomic segment accumulate ----------------
__global__ __launch_bounds__(256, 3)
void edge_kernel(const float* __restrict__ Eg,
                 const int* __restrict__ src, const int* __restrict__ dst,
                 const float* __restrict__ W1, const float* __restrict__ b1,
                 const float* __restrict__ W2, const float* __restrict__ b2,
                 const float* __restrict__ WB, const float* __restrict__ bB,
                 const float* __restrict__ WC, const float* __restrict__ bC,
                 const float* __restrict__ Vp,
                 float* __restrict__ S1, float* __restrict__ S2, float* __restrict__ deg)
{
    __shared__ float Wc[DDIM*PADX];
    __shared__ float XT[DDIM*PADX];
    __shared__ int srcs[64], dsts[64];
    const int tid = threadIdx.x;
    const int eb = blockIdx.x * 64;       // NE == 12500*64 exactly, no tail
    const int e0 = (tid & 15) << 2;
    const int f0 = (tid >> 4) << 2;

    // stage E tile (transposed) + indices + W1
    #pragma unroll
    for (int c = 0; c < 4; ++c) {
        int idx = (c << 10) + (tid << 2);
        int e = idx >> 6, d = idx & 63;
        float4 v = *(const float4*)&Eg[(size_t)(eb + e)*DDIM + d];
        XT[(d+0)*PADX + e] = v.x;
        XT[(d+1)*PADX + e] = v.y;
        XT[(d+2)*PADX + e] = v.z;
        XT[(d+3)*PADX + e] = v.w;
    }
    if (tid < 64)        srcs[tid]     = src[eb + tid];
    else if (tid < 128)  dsts[tid-64]  = dst[eb + tid - 64];
    load_w(Wc, W1, tid);
    __syncthreads();

    if (tid >= 128 && tid < 192) atomicAdd(&deg[dsts[tid-128]], 1.0f);

    // layer 1
    float acc[16];
    #pragma unroll
    for (int i = 0; i < 16; ++i) acc[i] = 0.f;
    mma_tile(acc, XT, Wc, e0, f0);
    __syncthreads();
    store_act<1>(XT, acc, *(const float4*)&b1[f0], e0, f0);
    load_w(Wc, W2, tid);
    __syncthreads();

    // layer 2
    #pragma unroll
    for (int i = 0; i < 16; ++i) acc[i] = 0.f;
    mma_tile(acc, XT, Wc, e0, f0);
    __syncthreads();
    store_act<1>(XT, acc, *(const float4*)&b2[f0], e0, f0);   // XT = x2
    load_w(Wc, WB, tid);
    __syncthreads();

    // scale pre-activation
    float accS[16];
    #pragma unroll
    for (int i = 0; i < 16; ++i) accS[i] = 0.f;
    mma_tile(accS, XT, Wc, e0, f0);
    __syncthreads();
    load_w(Wc, WC, tid);        // XT (x2) unchanged
    __syncthreads();

    // shift
    float accH[16];
    #pragma unroll
    for (int i = 0; i < 16; ++i) accH[i] = 0.f;
    mma_tile(accH, XT, Wc, e0, f0);

    // message + atomic accumulate
    float4 bBv = *(const float4*)&bB[f0];
    float4 bCv = *(const float4*)&bC[f0];
    const float bBa[4] = {bBv.x, bBv.y, bBv.z, bBv.w};
    const float bCa[4] = {bCv.x, bCv.y, bCv.z, bCv.w};
    #pragma unroll
    for (int i = 0; i < 4; ++i) {
        const int e  = e0 + i;
        const int sn = srcs[e];
        const int dn = dsts[e];
        float4 vp = *(const float4*)&Vp[(size_t)sn*DDIM + f0];
        const float vpa[4] = {vp.x, vp.y, vp.z, vp.w};
        #pragma unroll
        for (int j = 0; j < 4; ++j) {
            float sg = 1.0f / (1.0f + __expf(-(accS[i*4+j] + bBa[j])));
            float m1 = sg * vpa[j] + (accH[i*4+j] + bCa[j]);
            float m2 = m1 * m1;
            atomicAdd(&S1[(size_t)dn*DDIM + f0 + j], m1);
            atomicAdd(&S2[(size_t)dn*DDIM + f0 + j], m2);
        }
    }
}

// ---------------- finalize: out = sqrt(relu((S2-S1)/max(deg,1)) + eps) ----------------
__global__ __launch_bounds__(256)
void finalize_kernel(const float* __restrict__ S1, const float* __restrict__ S2,
                     const float* __restrict__ deg, float* __restrict__ out)
{
    int gid = blockIdx.x * blockDim.x + threadIdx.x;
    if (gid >= NN*DDIM) return;
    int n = gid >> 6;
    float dn = deg[n];
    dn = dn > 1.0f ? dn : 1.0f;
    float v = (S2[gid] - S1[gid]) / dn;
    out[gid] = sqrtf(fmaxf(v, 0.0f) + EPS_V);
}

extern "C" void kernel_launch(void* const* d_in, const int* in_sizes, int n_in,
                              void* d_out, int out_size, void* d_ws, size_t ws_size,
                              hipStream_t stream) {
    const float* V   = (const float*)d_in[0];
    const float* Eg  = (const float*)d_in[1];
    const int*   src = (const int*)d_in[2];
    const int*   dst = (const int*)d_in[3];
    const float* pAw = (const float*)d_in[4];
    const float* pAb = (const float*)d_in[5];
    const float* pBw = (const float*)d_in[6];
    const float* pBb = (const float*)d_in[7];
    const float* mW1 = (const float*)d_in[8];
    const float* mb1 = (const float*)d_in[9];
    const float* mW2 = (const float*)d_in[10];
    const float* mb2 = (const float*)d_in[11];
    const float* BW  = (const float*)d_in[12];
    const float* Bb  = (const float*)d_in[13];
    const float* CW  = (const float*)d_in[14];
    const float* Cb  = (const float*)d_in[15];
    float* out = (float*)d_out;

    float* ws  = (float*)d_ws;
    float* Vp  = ws;                          // NN*DDIM
    float* S1  = ws + (size_t)NN*DDIM;        // NN*DDIM
    float* S2  = ws + (size_t)2*NN*DDIM;      // NN*DDIM
    float* deg = ws + (size_t)3*NN*DDIM;      // NN

    // zero the accumulators (ws is poisoned before every call)
    hipMemsetAsync(S1, 0, (size_t)(2*NN*DDIM + NN) * sizeof(float), stream);

    node_pool_kernel<<<(NN + 63)/64, 256, 0, stream>>>(V, pAw, pAb, pBw, pBb, Vp);
    edge_kernel<<<NE/64, 256, 0, stream>>>(Eg, src, dst, mW1, mb1, mW2, mb2,
                                           BW, Bb, CW, Cb, Vp, S1, S2, deg);
    finalize_kernel<<<(NN*DDIM + 255)/256, 256, 0, stream>>>(S1, S2, deg, out);
}

// Round 2
// 788.257 us; speedup vs baseline: 2.1097x; 2.1097x over previous
//
#include <hip/hip_runtime.h>

#define NN 50000
#define NE 800000
#define DDIM 64
#define PADX 68          // padded LDS row stride (keeps 16B alignment, breaks pow2 banks)
#define NEG_SLOPE 0.2f
#define EPS_V 1e-5f

__device__ __forceinline__ float lrelu_f(float x) { return x >= 0.0f ? x : NEG_SLOPE * x; }

// acc[i*4+j] += sum_k XT[k][e0+i] * Wc[f0+j][k]
__device__ __forceinline__ void mma_tile(float acc[16], const float* __restrict__ XT,
                                         const float* __restrict__ Wc, int e0, int f0)
{
    #pragma unroll 4
    for (int kk = 0; kk < DDIM; kk += 4) {
        float4 A0 = *(const float4*)&XT[(kk+0)*PADX + e0];
        float4 A1 = *(const float4*)&XT[(kk+1)*PADX + e0];
        float4 A2 = *(const float4*)&XT[(kk+2)*PADX + e0];
        float4 A3 = *(const float4*)&XT[(kk+3)*PADX + e0];
        float4 B0 = *(const float4*)&Wc[(f0+0)*PADX + kk];
        float4 B1 = *(const float4*)&Wc[(f0+1)*PADX + kk];
        float4 B2 = *(const float4*)&Wc[(f0+2)*PADX + kk];
        float4 B3 = *(const float4*)&Wc[(f0+3)*PADX + kk];
        const float a[4][4] = {{A0.x,A0.y,A0.z,A0.w},{A1.x,A1.y,A1.z,A1.w},
                               {A2.x,A2.y,A2.z,A2.w},{A3.x,A3.y,A3.z,A3.w}};
        const float b[4][4] = {{B0.x,B0.y,B0.z,B0.w},{B1.x,B1.y,B1.z,B1.w},
                               {B2.x,B2.y,B2.z,B2.w},{B3.x,B3.y,B3.z,B3.w}};
        #pragma unroll
        for (int j = 0; j < 4; ++j)
            #pragma unroll
            for (int i = 0; i < 4; ++i)
                #pragma unroll
                for (int q = 0; q < 4; ++q)
                    acc[i*4+j] = fmaf(a[q][i], b[j][q], acc[i*4+j]);
    }
}

__device__ __forceinline__ void load_w(float* __restrict__ Wc, const float* __restrict__ Wg, int tid)
{
    #pragma unroll
    for (int c = 0; c < 4; ++c) {
        int idx = (c << 10) + (tid << 2);
        int f = idx >> 6, k = idx & 63;
        *(float4*)&Wc[f*PADX + k] = *(const float4*)&Wg[idx];
    }
}

// ACT: 0 = none, 1 = relu, 2 = lrelu
template<int ACT>
__device__ __forceinline__ void store_act(float* __restrict__ XT, const float acc[16],
                                          const float4 bv, int e0, int f0)
{
    const float ba[4] = {bv.x, bv.y, bv.z, bv.w};
    #pragma unroll
    for (int j = 0; j < 4; ++j) {
        float t0 = acc[0*4+j] + ba[j];
        float t1 = acc[1*4+j] + ba[j];
        float t2 = acc[2*4+j] + ba[j];
        float t3 = acc[3*4+j] + ba[j];
        if (ACT == 1) { t0 = fmaxf(t0,0.f); t1 = fmaxf(t1,0.f); t2 = fmaxf(t2,0.f); t3 = fmaxf(t3,0.f); }
        if (ACT == 2) { t0 = lrelu_f(t0); t1 = lrelu_f(t1); t2 = lrelu_f(t2); t3 = lrelu_f(t3); }
        float4 v; v.x = t0; v.y = t1; v.z = t2; v.w = t3;
        *(float4*)&XT[(f0+j)*PADX + e0] = v;
    }
}

// ---------------- node pooling ----------------
__global__ __launch_bounds__(256, 3)
void node_pool_kernel(const float* __restrict__ V,
                      const float* __restrict__ Aw, const float* __restrict__ Ab,
                      const float* __restrict__ Bw, const float* __restrict__ Bbv,
                      float* __restrict__ Vp)
{
    __shared__ float Wc[DDIM*PADX];
    __shared__ float XT[DDIM*PADX];
    const int tid = threadIdx.x;
    const int nb = blockIdx.x * 64;
    const int e0 = (tid & 15) << 2;
    const int f0 = (tid >> 4) << 2;

    #pragma unroll
    for (int c = 0; c < 4; ++c) {
        int idx = (c << 10) + (tid << 2);
        int e = idx >> 6, d = idx & 63;
        int row = nb + e; if (row > NN-1) row = NN-1;
        float4 v = *(const float4*)&V[(size_t)row*DDIM + d];
        XT[(d+0)*PADX + e] = lrelu_f(v.x);
        XT[(d+1)*PADX + e] = lrelu_f(v.y);
        XT[(d+2)*PADX + e] = lrelu_f(v.z);
        XT[(d+3)*PADX + e] = lrelu_f(v.w);
    }
    load_w(Wc, Aw, tid);
    __syncthreads();

    float acc[16];
    #pragma unroll
    for (int i = 0; i < 16; ++i) acc[i] = 0.f;
    mma_tile(acc, XT, Wc, e0, f0);
    __syncthreads();

    store_act<2>(XT, acc, *(const float4*)&Ab[f0], e0, f0);
    load_w(Wc, Bw, tid);
    __syncthreads();

    float acc2[16];
    #pragma unroll
    for (int i = 0; i < 16; ++i) acc2[i] = 0.f;
    mma_tile(acc2, XT, Wc, e0, f0);

    float4 bv = *(const float4*)&Bbv[f0];
    #pragma unroll
    for (int i = 0; i < 4; ++i) {
        int row = nb + e0 + i;
        if (row < NN) {
            float4 o;
            o.x = acc2[i*4+0] + bv.x;
            o.y = acc2[i*4+1] + bv.y;
            o.z = acc2[i*4+2] + bv.z;
            o.w = acc2[i*4+3] + bv.w;
            *(float4*)&Vp[(size_t)row*DDIM + f0] = o;
        }
    }
}

// ---------------- CSR build: histogram / scan / scatter ----------------
__global__ __launch_bounds__(256)
void hist_kernel(const int* __restrict__ dst, int* __restrict__ degi)
{
    int e = blockIdx.x * 256 + threadIdx.x;
    if (e < NE) atomicAdd(&degi[dst[e]], 1);
}

// single-block exclusive scan of degi[0..NN) -> offsets, cursor
__global__ __launch_bounds__(256)
void scan_kernel(const int* __restrict__ degi, int* __restrict__ offsets, int* __restrict__ cursor)
{
    __shared__ int wsum[4];
    __shared__ int sbase;
    const int tid = threadIdx.x;
    const int lane = tid & 63;
    const int wv = tid >> 6;
    if (tid == 0) sbase = 0;
    __syncthreads();
    for (int c0 = 0; c0 < NN; c0 += 1024) {
        int i0 = c0 + tid * 4;
        int v0 = 0, v1 = 0, v2 = 0, v3 = 0;
        if (i0 + 3 < NN) {
            int4 t = *(const int4*)&degi[i0];
            v0 = t.x; v1 = t.y; v2 = t.z; v3 = t.w;
        } else {
            if (i0     < NN) v0 = degi[i0];
            if (i0 + 1 < NN) v1 = degi[i0+1];
            if (i0 + 2 < NN) v2 = degi[i0+2];
            if (i0 + 3 < NN) v3 = degi[i0+3];
        }
        int lsum = v0 + v1 + v2 + v3;
        int sc = lsum;                       // inclusive wave scan
        #pragma unroll
        for (int off = 1; off < 64; off <<= 1) {
            int t = __shfl_up(sc, off, 64);
            if (lane >= off) sc += t;
        }
        if (lane == 63) wsum[wv] = sc;
        __syncthreads();
        int wb = 0;
        #pragma unroll
        for (int w = 0; w < 4; ++w) if (w < wv) wb += wsum[w];
        int base = sbase + wb + sc - lsum;   // exclusive prefix of this thread's 4
        if (i0     < NN) { offsets[i0]   = base; cursor[i0]   = base; }
        int b1 = base + v0;
        if (i0 + 1 < NN) { offsets[i0+1] = b1;   cursor[i0+1] = b1; }
        int b2 = b1 + v1;
        if (i0 + 2 < NN) { offsets[i0+2] = b2;   cursor[i0+2] = b2; }
        int b3 = b2 + v2;
        if (i0 + 3 < NN) { offsets[i0+3] = b3;   cursor[i0+3] = b3; }
        __syncthreads();
        if (tid == 255) sbase = sbase + wsum[0] + wsum[1] + wsum[2] + wsum[3];
        __syncthreads();
    }
}

__global__ __launch_bounds__(256)
void scatter_kernel(const int* __restrict__ dst, int* __restrict__ cursor, int* __restrict__ eidx)
{
    int e = blockIdx.x * 256 + threadIdx.x;
    if (e < NE) {
        int p = atomicAdd(&cursor[dst[e]], 1);
        eidx[p] = e;
    }
}

// ---------------- edge MLP + gated message + LDS-segmented accumulate ----------------
__global__ __launch_bounds__(256, 3)
void edge_kernel(const float* __restrict__ Eg,
                 const int* __restrict__ src, const int* __restrict__ dst,
                 const int* __restrict__ eidx,
                 const float* __restrict__ W1, const float* __restrict__ b1,
                 const float* __restrict__ W2, const float* __restrict__ b2,
                 const float* __restrict__ WB, const float* __restrict__ bB,
                 const float* __restrict__ WC, const float* __restrict__ bC,
                 const float* __restrict__ Vp,
                 float* __restrict__ S1, float* __restrict__ S2)
{
    __shared__ float Wc[DDIM*PADX];
    __shared__ float XT[DDIM*PADX];
    __shared__ int srcs[64], dsts[64];
    const int tid = threadIdx.x;
    const int eb = blockIdx.x * 64;       // NE == 12500*64 exactly
    const int e0 = (tid & 15) << 2;
    const int f0 = (tid >> 4) << 2;

    // stage E tile (transposed, via dst-sorted permutation) + indices + W1
    #pragma unroll
    for (int c = 0; c < 4; ++c) {
        int idx = (c << 10) + (tid << 2);
        int e = idx >> 6, d = idx & 63;
        int eg = eidx[eb + e];
        float4 v = *(const float4*)&Eg[(size_t)eg*DDIM + d];
        XT[(d+0)*PADX + e] = v.x;
        XT[(d+1)*PADX + e] = v.y;
        XT[(d+2)*PADX + e] = v.z;
        XT[(d+3)*PADX + e] = v.w;
    }
    if (tid < 64) {
        int eg = eidx[eb + tid];
        srcs[tid] = src[eg];
        dsts[tid] = dst[eg];
    }
    load_w(Wc, W1, tid);
    __syncthreads();

    // layer 1
    float acc[16];
    #pragma unroll
    for (int i = 0; i < 16; ++i) acc[i] = 0.f;
    mma_tile(acc, XT, Wc, e0, f0);
    __syncthreads();
    store_act<1>(XT, acc, *(const float4*)&b1[f0], e0, f0);
    load_w(Wc, W2, tid);
    __syncthreads();

    // layer 2
    #pragma unroll
    for (int i = 0; i < 16; ++i) acc[i] = 0.f;
    mma_tile(acc, XT, Wc, e0, f0);
    __syncthreads();
    store_act<1>(XT, acc, *(const float4*)&b2[f0], e0, f0);   // XT = x2
    load_w(Wc, WB, tid);
    __syncthreads();

    // scale pre-activation
    float accS[16];
    #pragma unroll
    for (int i = 0; i < 16; ++i) accS[i] = 0.f;
    mma_tile(accS, XT, Wc, e0, f0);
    __syncthreads();
    load_w(Wc, WC, tid);        // XT (x2) unchanged
    __syncthreads();

    // shift
    float accH[16];
    #pragma unroll
    for (int i = 0; i < 16; ++i) accH[i] = 0.f;
    mma_tile(accH, XT, Wc, e0, f0);
    __syncthreads();            // everyone done reading XT/Wc — reuse as message tiles

    float* M1T = XT;            // [f][e], stride PADX
    float* M2T = Wc;

    float4 bBv = *(const float4*)&bB[f0];
    float4 bCv = *(const float4*)&bC[f0];
    const float bBa[4] = {bBv.x, bBv.y, bBv.z, bBv.w};
    const float bCa[4] = {bCv.x, bCv.y, bCv.z, bCv.w};
    #pragma unroll
    for (int i = 0; i < 4; ++i) {
        const int e  = e0 + i;
        const int sn = srcs[e];
        float4 vp = *(const float4*)&Vp[(size_t)sn*DDIM + f0];
        const float vpa[4] = {vp.x, vp.y, vp.z, vp.w};
        #pragma unroll
        for (int j = 0; j < 4; ++j) {
            float sg = 1.0f / (1.0f + __expf(-(accS[i*4+j] + bBa[j])));
            float m1 = sg * vpa[j] + (accH[i*4+j] + bCa[j]);
            M1T[(f0+j)*PADX + e] = m1;
            M2T[(f0+j)*PADX + e] = m1 * m1;
        }
    }
    __syncthreads();

    // segmented reduction: thread = (feature f, 16-edge group g); edges sorted by dst
    const int f = tid >> 2;
    const int g = (tid & 3) << 4;
    float s1 = 0.f, s2 = 0.f;
    int prev = dsts[g];
    #pragma unroll 4
    for (int i = 0; i < 16; ++i) {
        int dn = dsts[g + i];
        float m1 = M1T[f*PADX + g + i];
        float m2 = M2T[f*PADX + g + i];
        if (dn != prev) {
            atomicAdd(&S1[(size_t)prev*DDIM + f], s1);
            atomicAdd(&S2[(size_t)prev*DDIM + f], s2);
            s1 = 0.f; s2 = 0.f; prev = dn;
        }
        s1 += m1; s2 += m2;
    }
    atomicAdd(&S1[(size_t)prev*DDIM + f], s1);
    atomicAdd(&S2[(size_t)prev*DDIM + f], s2);
}

// ---------------- finalize ----------------
__global__ __launch_bounds__(256)
void finalize_kernel(const float* __restrict__ S1, const float* __restrict__ S2,
                     const int* __restrict__ degi, float* __restrict__ out)
{
    int gid = blockIdx.x * blockDim.x + threadIdx.x;
    if (gid >= NN*DDIM) return;
    int n = gid >> 6;
    float dn = (float)degi[n];
    dn = dn > 1.0f ? dn : 1.0f;
    float v = (S2[gid] - S1[gid]) / dn;
    out[gid] = sqrtf(fmaxf(v, 0.0f) + EPS_V);
}

extern "C" void kernel_launch(void* const* d_in, const int* in_sizes, int n_in,
                              void* d_out, int out_size, void* d_ws, size_t ws_size,
                              hipStream_t stream) {
    const float* V   = (const float*)d_in[0];
    const float* Eg  = (const float*)d_in[1];
    const int*   src = (const int*)d_in[2];
    const int*   dst = (const int*)d_in[3];
    const float* pAw = (const float*)d_in[4];
    const float* pAb = (const float*)d_in[5];
    const float* pBw = (const float*)d_in[6];
    const float* pBb = (const float*)d_in[7];
    const float* mW1 = (const float*)d_in[8];
    const float* mb1 = (const float*)d_in[9];
    const float* mW2 = (const float*)d_in[10];
    const float* mb2 = (const float*)d_in[11];
    const float* BW  = (const float*)d_in[12];
    const float* Bb  = (const float*)d_in[13];
    const float* CW  = (const float*)d_in[14];
    const float* Cb  = (const float*)d_in[15];
    float* out = (float*)d_out;

    float* ws   = (float*)d_ws;
    float* Vp   = ws;                                   // NN*DDIM f32
    float* S1   = ws + (size_t)NN*DDIM;                 // NN*DDIM f32
    float* S2   = ws + (size_t)2*NN*DDIM;               // NN*DDIM f32
    int*   degi = (int*)(ws + (size_t)3*NN*DDIM);       // NN i32
    int*   offs = degi + NN;                            // NN i32
    int*   curs = offs + NN;                            // NN i32
    int*   eidx = curs + NN;                            // NE i32

    // zero S1, S2, degi (contiguous)
    hipMemsetAsync(S1, 0, (size_t)(2*NN*DDIM + NN) * sizeof(float), stream);

    node_pool_kernel<<<(NN + 63)/64, 256, 0, stream>>>(V, pAw, pAb, pBw, pBb, Vp);
    hist_kernel<<<(NE + 255)/256, 256, 0, stream>>>(dst, degi);
    scan_kernel<<<1, 256, 0, stream>>>(degi, offs, curs);
    scatter_kernel<<<(NE + 255)/256, 256, 0, stream>>>(dst, curs, eidx);
    edge_kernel<<<NE/64, 256, 0, stream>>>(Eg, src, dst, eidx, mW1, mb1, mW2, mb2,
                                           BW, Bb, CW, Cb, Vp, S1, S2);
    finalize_kernel<<<(NN*DDIM + 255)/256, 256, 0, stream>>>(S1, S2, degi, out);
}

// Round 3
// 597.972 us; speedup vs baseline: 2.7810x; 1.3182x over previous
//
#include <hip/hip_runtime.h>

#define NN 50000
#define NE 800000
#define DDIM 64
#define PADX 68          // fp32 LDS row stride (message tiles, node pool)
#define PADK 72          // bf16 LDS row stride (MFMA staging): 144 B rows
#define NB_SCAN ((NN + 255) / 256)   // 196
#define NEG_SLOPE 0.2f
#define EPS_V 1e-5f

typedef short bf16x8 __attribute__((ext_vector_type(8)));
typedef float f32x4 __attribute__((ext_vector_type(4)));

__device__ __forceinline__ float lrelu_f(float x) { return x >= 0.0f ? x : NEG_SLOPE * x; }

__device__ __forceinline__ unsigned short bf16_rn(float x) {
    union { float f; unsigned int u; } c; c.f = x;
    unsigned int r = c.u + 0x7FFF + ((c.u >> 16) & 1);
    return (unsigned short)(r >> 16);
}
__device__ __forceinline__ float bf16_tof(unsigned short h) {
    union { float f; unsigned int u; } c; c.u = ((unsigned int)h) << 16;
    return c.f;
}

// ---------------- fp32 micro-tile GEMM helpers (node pooling only) ----------------
__device__ __forceinline__ void mma_tile(float acc[16], const float* __restrict__ XT,
                                         const float* __restrict__ Wc, int e0, int f0)
{
    #pragma unroll 4
    for (int kk = 0; kk < DDIM; kk += 4) {
        float4 A0 = *(const float4*)&XT[(kk+0)*PADX + e0];
        float4 A1 = *(const float4*)&XT[(kk+1)*PADX + e0];
        float4 A2 = *(const float4*)&XT[(kk+2)*PADX + e0];
        float4 A3 = *(const float4*)&XT[(kk+3)*PADX + e0];
        float4 B0 = *(const float4*)&Wc[(f0+0)*PADX + kk];
        float4 B1 = *(const float4*)&Wc[(f0+1)*PADX + kk];
        float4 B2 = *(const float4*)&Wc[(f0+2)*PADX + kk];
        float4 B3 = *(const float4*)&Wc[(f0+3)*PADX + kk];
        const float a[4][4] = {{A0.x,A0.y,A0.z,A0.w},{A1.x,A1.y,A1.z,A1.w},
                               {A2.x,A2.y,A2.z,A2.w},{A3.x,A3.y,A3.z,A3.w}};
        const float b[4][4] = {{B0.x,B0.y,B0.z,B0.w},{B1.x,B1.y,B1.z,B1.w},
                               {B2.x,B2.y,B2.z,B2.w},{B3.x,B3.y,B3.z,B3.w}};
        #pragma unroll
        for (int j = 0; j < 4; ++j)
            #pragma unroll
            for (int i = 0; i < 4; ++i)
                #pragma unroll
                for (int q = 0; q < 4; ++q)
                    acc[i*4+j] = fmaf(a[q][i], b[j][q], acc[i*4+j]);
    }
}

__device__ __forceinline__ void load_w_f32(float* __restrict__ Wc, const float* __restrict__ Wg, int tid)
{
    #pragma unroll
    for (int c = 0; c < 4; ++c) {
        int idx = (c << 10) + (tid << 2);
        int f = idx >> 6, k = idx & 63;
        *(float4*)&Wc[f*PADX + k] = *(const float4*)&Wg[idx];
    }
}

// ---------------- node pooling (fp32 path, small: 782 blocks) ----------------
__global__ __launch_bounds__(256, 3)
void node_pool_kernel(const float* __restrict__ V,
                      const float* __restrict__ Aw, const float* __restrict__ Ab,
                      const float* __restrict__ Bw, const float* __restrict__ Bbv,
                      float* __restrict__ Vp)
{
    __shared__ float Wc[DDIM*PADX];
    __shared__ float XT[DDIM*PADX];
    const int tid = threadIdx.x;
    const int nb = blockIdx.x * 64;
    const int e0 = (tid & 15) << 2;
    const int f0 = (tid >> 4) << 2;

    #pragma unroll
    for (int c = 0; c < 4; ++c) {
        int idx = (c << 10) + (tid << 2);
        int e = idx >> 6, d = idx & 63;
        int row = nb + e; if (row > NN-1) row = NN-1;
        float4 v = *(const float4*)&V[(size_t)row*DDIM + d];
        XT[(d+0)*PADX + e] = lrelu_f(v.x);
        XT[(d+1)*PADX + e] = lrelu_f(v.y);
        XT[(d+2)*PADX + e] = lrelu_f(v.z);
        XT[(d+3)*PADX + e] = lrelu_f(v.w);
    }
    load_w_f32(Wc, Aw, tid);
    __syncthreads();

    float acc[16];
    #pragma unroll
    for (int i = 0; i < 16; ++i) acc[i] = 0.f;
    mma_tile(acc, XT, Wc, e0, f0);
    __syncthreads();

    {   // lrelu(acc + Ab) -> XT
        float4 bv = *(const float4*)&Ab[f0];
        const float ba[4] = {bv.x, bv.y, bv.z, bv.w};
        #pragma unroll
        for (int j = 0; j < 4; ++j) {
            float4 v;
            v.x = lrelu_f(acc[0*4+j] + ba[j]);
            v.y = lrelu_f(acc[1*4+j] + ba[j]);
            v.z = lrelu_f(acc[2*4+j] + ba[j]);
            v.w = lrelu_f(acc[3*4+j] + ba[j]);
            *(float4*)&XT[(f0+j)*PADX + e0] = v;
        }
    }
    load_w_f32(Wc, Bw, tid);
    __syncthreads();

    float acc2[16];
    #pragma unroll
    for (int i = 0; i < 16; ++i) acc2[i] = 0.f;
    mma_tile(acc2, XT, Wc, e0, f0);

    float4 bv = *(const float4*)&Bbv[f0];
    #pragma unroll
    for (int i = 0; i < 4; ++i) {
        int row = nb + e0 + i;
        if (row < NN) {
            float4 o;
            o.x = acc2[i*4+0] + bv.x;
            o.y = acc2[i*4+1] + bv.y;
            o.z = acc2[i*4+2] + bv.z;
            o.w = acc2[i*4+3] + bv.w;
            *(float4*)&Vp[(size_t)row*DDIM + f0] = o;
        }
    }
}

// ---------------- CSR build: histogram / 3-pass scan / scatter ----------------
__global__ __launch_bounds__(256)
void hist_kernel(const int* __restrict__ dst, int* __restrict__ degi)
{
    int e = blockIdx.x * 256 + threadIdx.x;
    if (e < NE) atomicAdd(&degi[dst[e]], 1);
}

// per-block inclusive scan of 256 values + block total
__global__ __launch_bounds__(256)
void scan1_kernel(const int* __restrict__ degi, int* __restrict__ linc, int* __restrict__ bsum)
{
    __shared__ int ws[4];
    const int tid = threadIdx.x;
    const int lane = tid & 63, wv = tid >> 6;
    int i = blockIdx.x * 256 + tid;
    int v = (i < NN) ? degi[i] : 0;
    int sc = v;
    #pragma unroll
    for (int off = 1; off < 64; off <<= 1) {
        int t = __shfl_up(sc, off, 64);
        if (lane >= off) sc += t;
    }
    if (lane == 63) ws[wv] = sc;
    __syncthreads();
    int wb = 0;
    #pragma unroll
    for (int w = 0; w < 4; ++w) if (w < wv) wb += ws[w];
    int incl = sc + wb;
    if (i < NN) linc[i] = incl;
    if (tid == 255) bsum[blockIdx.x] = incl;
}

// single block: exclusive scan of NB_SCAN block sums
__global__ __launch_bounds__(256)
void scan2_kernel(const int* __restrict__ bsum, int* __restrict__ bbase)
{
    __shared__ int ws[4];
    const int tid = threadIdx.x;
    const int lane = tid & 63, wv = tid >> 6;
    int v = (tid < NB_SCAN) ? bsum[tid] : 0;
    int sc = v;
    #pragma unroll
    for (int off = 1; off < 64; off <<= 1) {
        int t = __shfl_up(sc, off, 64);
        if (lane >= off) sc += t;
    }
    if (lane == 63) ws[wv] = sc;
    __syncthreads();
    int wb = 0;
    #pragma unroll
    for (int w = 0; w < 4; ++w) if (w < wv) wb += ws[w];
    if (tid < NB_SCAN) bbase[tid] = sc + wb - v;   // exclusive
}

// cursor[i] = bbase[b] + linc[i] - degi[i]  (global exclusive prefix)
__global__ __launch_bounds__(256)
void scan3_kernel(const int* __restrict__ degi, const int* __restrict__ linc,
                  const int* __restrict__ bbase, int* __restrict__ curs)
{
    int i = blockIdx.x * 256 + threadIdx.x;
    if (i < NN) curs[i] = bbase[blockIdx.x] + linc[i] - degi[i];
}

__global__ __launch_bounds__(256)
void scatter_kernel(const int* __restrict__ dst, int* __restrict__ cursor, int* __restrict__ eidx)
{
    int e = blockIdx.x * 256 + threadIdx.x;
    if (e < NE) {
        int p = atomicAdd(&cursor[dst[e]], 1);
        eidx[p] = e;
    }
}

// ---------------- split-bf16 MFMA edge kernel ----------------
// stage a 64x64 fp32 weight (row-major [f][k]) into hi/lo bf16 LDS, stride PADK
__device__ __forceinline__ void stage_w(short* __restrict__ Wh, short* __restrict__ Wl,
                                        const float* __restrict__ Wg, int tid)
{
    #pragma unroll
    for (int c = 0; c < 4; ++c) {
        int idx = (c << 10) + (tid << 2);
        int f = idx >> 6, k = idx & 63;
        float4 v = *(const float4*)&Wg[idx];
        ushort4 h, l;
        h.x = bf16_rn(v.x); l.x = bf16_rn(v.x - bf16_tof(h.x));
        h.y = bf16_rn(v.y); l.y = bf16_rn(v.y - bf16_tof(h.y));
        h.z = bf16_rn(v.z); l.z = bf16_rn(v.z - bf16_tof(h.z));
        h.w = bf16_rn(v.w); l.w = bf16_rn(v.w - bf16_tof(h.w));
        *(ushort4*)&Wh[f*PADK + k] = h;
        *(ushort4*)&Wl[f*PADK + k] = l;
    }
}

// per-wave: 16-edge strip (wv*16..+15) x 64 features, K=64, split-bf16 (3 MFMAs)
__device__ __forceinline__ void mfma_gemm(const short* __restrict__ Xh, const short* __restrict__ Xl,
                                          const short* __restrict__ Wh, const short* __restrict__ Wl,
                                          int wv, int lane, f32x4 acc[4])
{
    const int m = lane & 15, kg = lane >> 4;
    const int arow = (wv*16 + m)*PADK + kg*8;
    #pragma unroll
    for (int ks = 0; ks < 2; ++ks) {
        bf16x8 ah = *(const bf16x8*)&Xh[arow + ks*32];
        bf16x8 al = *(const bf16x8*)&Xl[arow + ks*32];
        #pragma unroll
        for (int t = 0; t < 4; ++t) {
            int boff = (t*16 + m)*PADK + kg*8 + ks*32;
            bf16x8 bh = *(const bf16x8*)&Wh[boff];
            bf16x8 bl = *(const bf16x8*)&Wl[boff];
            acc[t] = __builtin_amdgcn_mfma_f32_16x16x32_bf16(al, bh, acc[t], 0, 0, 0);
            acc[t] = __builtin_amdgcn_mfma_f32_16x16x32_bf16(ah, bl, acc[t], 0, 0, 0);
            acc[t] = __builtin_amdgcn_mfma_f32_16x16x32_bf16(ah, bh, acc[t], 0, 0, 0);
        }
    }
}

// D-layout (col=lane&15 -> feature, row=(lane>>4)*4+reg -> edge) + bias + relu
// -> back into Xh/Xl as next layer's A operand (X[e][f])
__device__ __forceinline__ void repack_relu(short* __restrict__ Xh, short* __restrict__ Xl,
                                            const f32x4 acc[4], const float* __restrict__ bias,
                                            int wv, int lane)
{
    const int n = lane & 15, mg = lane >> 4;
    #pragma unroll
    for (int t = 0; t < 4; ++t) {
        float b = bias[t*16 + n];
        #pragma unroll
        for (int r = 0; r < 4; ++r) {
            float y = fmaxf(acc[t][r] + b, 0.0f);
            int e = wv*16 + mg*4 + r;
            unsigned short h = bf16_rn(y);
            float lof = y - bf16_tof(h);
            Xh[e*PADK + t*16 + n] = (short)h;
            Xl[e*PADK + t*16 + n] = (short)bf16_rn(lof);
        }
    }
}

__global__ __launch_bounds__(256, 4)
void edge_kernel(const float* __restrict__ Eg,
                 const int* __restrict__ src, const int* __restrict__ dst,
                 const int* __restrict__ eidx,
                 const float* __restrict__ W1, const float* __restrict__ b1,
                 const float* __restrict__ W2, const float* __restrict__ b2,
                 const float* __restrict__ WB, const float* __restrict__ bB,
                 const float* __restrict__ WC, const float* __restrict__ bC,
                 const float* __restrict__ Vp,
                 float* __restrict__ S1, float* __restrict__ S2)
{
    __shared__ __align__(16) char smem[4 * 64 * PADK * 2];   // 36864 B, aliased
    __shared__ int srcs[64], dsts[64];
    short* Xh = (short*)smem;
    short* Xl = Xh + 64*PADK;
    short* Wh = Xl + 64*PADK;
    short* Wl = Wh + 64*PADK;
    float* M1T = (float*)smem;            // [f][e] stride PADX, aliases X/W bufs
    float* M2T = M1T + 64*PADX;

    const int tid = threadIdx.x;
    const int lane = tid & 63, wv = tid >> 6;
    const int eb = blockIdx.x * 64;       // NE == 12500*64 exactly

    // stage E tile (dst-sorted permutation) as hi/lo bf16 X[e][k]
    #pragma unroll
    for (int c = 0; c < 4; ++c) {
        int idx = (c << 10) + (tid << 2);
        int e = idx >> 6, d = idx & 63;
        int eg = eidx[eb + e];
        float4 v = *(const float4*)&Eg[(size_t)eg*DDIM + d];
        ushort4 h, l;
        h.x = bf16_rn(v.x); l.x = bf16_rn(v.x - bf16_tof(h.x));
        h.y = bf16_rn(v.y); l.y = bf16_rn(v.y - bf16_tof(h.y));
        h.z = bf16_rn(v.z); l.z = bf16_rn(v.z - bf16_tof(h.z));
        h.w = bf16_rn(v.w); l.w = bf16_rn(v.w - bf16_tof(h.w));
        *(ushort4*)&Xh[e*PADK + d] = h;
        *(ushort4*)&Xl[e*PADK + d] = l;
    }
    if (tid < 64) {
        int eg = eidx[eb + tid];
        srcs[tid] = src[eg];
        dsts[tid] = dst[eg];
    }
    stage_w(Wh, Wl, W1, tid);
    __syncthreads();

    // layer 1
    f32x4 acc[4];
    #pragma unroll
    for (int t = 0; t < 4; ++t) acc[t] = (f32x4){0.f, 0.f, 0.f, 0.f};
    mfma_gemm(Xh, Xl, Wh, Wl, wv, lane, acc);
    __syncthreads();                       // all MFMA reads done
    repack_relu(Xh, Xl, acc, b1, wv, lane);
    stage_w(Wh, Wl, W2, tid);
    __syncthreads();

    // layer 2
    #pragma unroll
    for (int t = 0; t < 4; ++t) acc[t] = (f32x4){0.f, 0.f, 0.f, 0.f};
    mfma_gemm(Xh, Xl, Wh, Wl, wv, lane, acc);
    __syncthreads();
    repack_relu(Xh, Xl, acc, b2, wv, lane);   // X = x2
    stage_w(Wh, Wl, WB, tid);
    __syncthreads();

    // scale pre-activation
    f32x4 accS[4];
    #pragma unroll
    for (int t = 0; t < 4; ++t) accS[t] = (f32x4){0.f, 0.f, 0.f, 0.f};
    mfma_gemm(Xh, Xl, Wh, Wl, wv, lane, accS);
    __syncthreads();
    stage_w(Wh, Wl, WC, tid);             // X (x2) unchanged
    __syncthreads();

    // shift pre-activation
    f32x4 accH[4];
    #pragma unroll
    for (int t = 0; t < 4; ++t) accH[t] = (f32x4){0.f, 0.f, 0.f, 0.f};
    mfma_gemm(Xh, Xl, Wh, Wl, wv, lane, accH);
    __syncthreads();                      // done with X/W — alias as M1T/M2T

    // D-layout -> [f][e] fp32 tiles (raw pre-bias)
    {
        const int n = lane & 15, mg = lane >> 4;
        #pragma unroll
        for (int t = 0; t < 4; ++t)
            #pragma unroll
            for (int r = 0; r < 4; ++r) {
                int f = t*16 + n;
                int e = wv*16 + mg*4 + r;
                M1T[f*PADX + e] = accS[t][r];
                M2T[f*PADX + e] = accH[t][r];
            }
    }
    __syncthreads();

    // message phase (round-2 mapping: thread owns e0..e0+3 x f0..f0+3)
    const int e0 = (tid & 15) << 2;
    const int f0 = (tid >> 4) << 2;
    {
        float4 bBv = *(const float4*)&bB[f0];
        float4 bCv = *(const float4*)&bC[f0];
        const float bBa[4] = {bBv.x, bBv.y, bBv.z, bBv.w};
        const float bCa[4] = {bCv.x, bCv.y, bCv.z, bCv.w};
        #pragma unroll
        for (int i = 0; i < 4; ++i) {
            const int e  = e0 + i;
            const int sn = srcs[e];
            float4 vp = *(const float4*)&Vp[(size_t)sn*DDIM + f0];
            const float vpa[4] = {vp.x, vp.y, vp.z, vp.w};
            #pragma unroll
            for (int j = 0; j < 4; ++j) {
                float sPre = M1T[(f0+j)*PADX + e] + bBa[j];
                float hPre = M2T[(f0+j)*PADX + e] + bCa[j];
                float sg = 1.0f / (1.0f + __expf(-sPre));
                float m1 = sg * vpa[j] + hPre;
                M1T[(f0+j)*PADX + e] = m1;
                M2T[(f0+j)*PADX + e] = m1 * m1;
            }
        }
    }
    __syncthreads();

    // segmented reduction: thread = (feature f, 16-edge group g); edges sorted by dst
    const int f = tid >> 2;
    const int g = (tid & 3) << 4;
    float s1 = 0.f, s2 = 0.f;
    int prev = dsts[g];
    #pragma unroll 4
    for (int i = 0; i < 16; ++i) {
        int dn = dsts[g + i];
        float m1 = M1T[f*PADX + g + i];
        float m2 = M2T[f*PADX + g + i];
        if (dn != prev) {
            atomicAdd(&S1[(size_t)prev*DDIM + f], s1);
            atomicAdd(&S2[(size_t)prev*DDIM + f], s2);
            s1 = 0.f; s2 = 0.f; prev = dn;
        }
        s1 += m1; s2 += m2;
    }
    atomicAdd(&S1[(size_t)prev*DDIM + f], s1);
    atomicAdd(&S2[(size_t)prev*DDIM + f], s2);
}

// ---------------- finalize ----------------
__global__ __launch_bounds__(256)
void finalize_kernel(const float* __restrict__ S1, const float* __restrict__ S2,
                     const int* __restrict__ degi, float* __restrict__ out)
{
    int gid = blockIdx.x * blockDim.x + threadIdx.x;
    if (gid >= NN*DDIM) return;
    int n = gid >> 6;
    float dn = (float)degi[n];
    dn = dn > 1.0f ? dn : 1.0f;
    float v = (S2[gid] - S1[gid]) / dn;
    out[gid] = sqrtf(fmaxf(v, 0.0f) + EPS_V);
}

extern "C" void kernel_launch(void* const* d_in, const int* in_sizes, int n_in,
                              void* d_out, int out_size, void* d_ws, size_t ws_size,
                              hipStream_t stream) {
    const float* V   = (const float*)d_in[0];
    const float* Eg  = (const float*)d_in[1];
    const int*   src = (const int*)d_in[2];
    const int*   dst = (const int*)d_in[3];
    const float* pAw = (const float*)d_in[4];
    const float* pAb = (const float*)d_in[5];
    const float* pBw = (const float*)d_in[6];
    const float* pBb = (const float*)d_in[7];
    const float* mW1 = (const float*)d_in[8];
    const float* mb1 = (const float*)d_in[9];
    const float* mW2 = (const float*)d_in[10];
    const float* mb2 = (const float*)d_in[11];
    const float* BW  = (const float*)d_in[12];
    const float* Bb  = (const float*)d_in[13];
    const float* CW  = (const float*)d_in[14];
    const float* Cb  = (const float*)d_in[15];
    float* out = (float*)d_out;

    float* ws    = (float*)d_ws;
    float* Vp    = ws;                                   // NN*DDIM f32
    float* S1    = ws + (size_t)NN*DDIM;                 // NN*DDIM f32
    float* S2    = ws + (size_t)2*NN*DDIM;               // NN*DDIM f32
    int*   degi  = (int*)(ws + (size_t)3*NN*DDIM);       // NN i32
    int*   curs  = degi + NN;                            // NN i32
    int*   linc  = curs + NN;                            // NN i32
    int*   bsum  = linc + NN;                            // NB_SCAN i32
    int*   bbase = bsum + NB_SCAN;                       // NB_SCAN i32
    int*   eidx  = bbase + NB_SCAN;                      // NE i32

    // zero S1, S2, degi (contiguous)
    hipMemsetAsync(S1, 0, (size_t)(2*NN*DDIM + NN) * sizeof(float), stream);

    node_pool_kernel<<<(NN + 63)/64, 256, 0, stream>>>(V, pAw, pAb, pBw, pBb, Vp);
    hist_kernel<<<(NE + 255)/256, 256, 0, stream>>>(dst, degi);
    scan1_kernel<<<NB_SCAN, 256, 0, stream>>>(degi, linc, bsum);
    scan2_kernel<<<1, 256, 0, stream>>>(bsum, bbase);
    scan3_kernel<<<NB_SCAN, 256, 0, stream>>>(degi, linc, bbase, curs);
    scatter_kernel<<<(NE + 255)/256, 256, 0, stream>>>(dst, curs, eidx);
    edge_kernel<<<NE/64, 256, 0, stream>>>(Eg, src, dst, eidx, mW1, mb1, mW2, mb2,
                                           BW, Bb, CW, Cb, Vp, S1, S2);
    finalize_kernel<<<(NN*DDIM + 255)/256, 256, 0, stream>>>(S1, S2, degi, out);
}

// Round 4
// 584.370 us; speedup vs baseline: 2.8457x; 1.0233x over previous
//
#include <hip/hip_runtime.h>

#define NN 50000
#define NE 800000
#define DDIM 64
#define PADX 68          // fp32 LDS row stride (node pool)
#define PADK 72          // bf16 LDS row stride (MFMA X staging)
#define PADM 69          // fp32 M1 tile stride: 5f+e bank map -> <=2-way conflicts
#define NB_SCAN ((NN + 255) / 256)   // 196
#define NEG_SLOPE 0.2f
#define EPS_V 1e-5f

typedef short bf16x8 __attribute__((ext_vector_type(8)));
typedef float f32x4 __attribute__((ext_vector_type(4)));

__device__ __forceinline__ float lrelu_f(float x) { return x >= 0.0f ? x : NEG_SLOPE * x; }

__device__ __forceinline__ unsigned short bf16_rn(float x) {
    union { float f; unsigned int u; } c; c.f = x;
    unsigned int r = c.u + 0x7FFF + ((c.u >> 16) & 1);
    return (unsigned short)(r >> 16);
}
__device__ __forceinline__ float bf16_tof(unsigned short h) {
    union { float f; unsigned int u; } c; c.u = ((unsigned int)h) << 16;
    return c.f;
}

// ---------------- fp32 micro-tile GEMM helpers (node pooling only) ----------------
__device__ __forceinline__ void mma_tile(float acc[16], const float* __restrict__ XT,
                                         const float* __restrict__ Wc, int e0, int f0)
{
    #pragma unroll 4
    for (int kk = 0; kk < DDIM; kk += 4) {
        float4 A0 = *(const float4*)&XT[(kk+0)*PADX + e0];
        float4 A1 = *(const float4*)&XT[(kk+1)*PADX + e0];
        float4 A2 = *(const float4*)&XT[(kk+2)*PADX + e0];
        float4 A3 = *(const float4*)&XT[(kk+3)*PADX + e0];
        float4 B0 = *(const float4*)&Wc[(f0+0)*PADX + kk];
        float4 B1 = *(const float4*)&Wc[(f0+1)*PADX + kk];
        float4 B2 = *(const float4*)&Wc[(f0+2)*PADX + kk];
        float4 B3 = *(const float4*)&Wc[(f0+3)*PADX + kk];
        const float a[4][4] = {{A0.x,A0.y,A0.z,A0.w},{A1.x,A1.y,A1.z,A1.w},
                               {A2.x,A2.y,A2.z,A2.w},{A3.x,A3.y,A3.z,A3.w}};
        const float b[4][4] = {{B0.x,B0.y,B0.z,B0.w},{B1.x,B1.y,B1.z,B1.w},
                               {B2.x,B2.y,B2.z,B2.w},{B3.x,B3.y,B3.z,B3.w}};
        #pragma unroll
        for (int j = 0; j < 4; ++j)
            #pragma unroll
            for (int i = 0; i < 4; ++i)
                #pragma unroll
                for (int q = 0; q < 4; ++q)
                    acc[i*4+j] = fmaf(a[q][i], b[j][q], acc[i*4+j]);
    }
}

__device__ __forceinline__ void load_w_f32(float* __restrict__ Wc, const float* __restrict__ Wg, int tid)
{
    #pragma unroll
    for (int c = 0; c < 4; ++c) {
        int idx = (c << 10) + (tid << 2);
        int f = idx >> 6, k = idx & 63;
        *(float4*)&Wc[f*PADX + k] = *(const float4*)&Wg[idx];
    }
}

// ---------------- node pooling (fp32) + fused dst histogram ----------------
__global__ __launch_bounds__(256, 3)
void node_pool_kernel(const float* __restrict__ V,
                      const float* __restrict__ Aw, const float* __restrict__ Ab,
                      const float* __restrict__ Bw, const float* __restrict__ Bbv,
                      float* __restrict__ Vp,
                      const int* __restrict__ dst, int* __restrict__ degi)
{
    __shared__ float Wc[DDIM*PADX];
    __shared__ float XT[DDIM*PADX];
    const int tid = threadIdx.x;
    const int nb = blockIdx.x * 64;
    const int e0 = (tid & 15) << 2;
    const int f0 = (tid >> 4) << 2;

    #pragma unroll
    for (int c = 0; c < 4; ++c) {
        int idx = (c << 10) + (tid << 2);
        int e = idx >> 6, d = idx & 63;
        int row = nb + e; if (row > NN-1) row = NN-1;
        float4 v = *(const float4*)&V[(size_t)row*DDIM + d];
        XT[(d+0)*PADX + e] = lrelu_f(v.x);
        XT[(d+1)*PADX + e] = lrelu_f(v.y);
        XT[(d+2)*PADX + e] = lrelu_f(v.z);
        XT[(d+3)*PADX + e] = lrelu_f(v.w);
    }
    load_w_f32(Wc, Aw, tid);
    __syncthreads();

    float acc[16];
    #pragma unroll
    for (int i = 0; i < 16; ++i) acc[i] = 0.f;
    mma_tile(acc, XT, Wc, e0, f0);
    __syncthreads();

    {   // lrelu(acc + Ab) -> XT
        float4 bv = *(const float4*)&Ab[f0];
        const float ba[4] = {bv.x, bv.y, bv.z, bv.w};
        #pragma unroll
        for (int j = 0; j < 4; ++j) {
            float4 v;
            v.x = lrelu_f(acc[0*4+j] + ba[j]);
            v.y = lrelu_f(acc[1*4+j] + ba[j]);
            v.z = lrelu_f(acc[2*4+j] + ba[j]);
            v.w = lrelu_f(acc[3*4+j] + ba[j]);
            *(float4*)&XT[(f0+j)*PADX + e0] = v;
        }
    }
    load_w_f32(Wc, Bw, tid);
    __syncthreads();

    float acc2[16];
    #pragma unroll
    for (int i = 0; i < 16; ++i) acc2[i] = 0.f;
    mma_tile(acc2, XT, Wc, e0, f0);

    float4 bv = *(const float4*)&Bbv[f0];
    #pragma unroll
    for (int i = 0; i < 4; ++i) {
        int row = nb + e0 + i;
        if (row < NN) {
            float4 o;
            o.x = acc2[i*4+0] + bv.x;
            o.y = acc2[i*4+1] + bv.y;
            o.z = acc2[i*4+2] + bv.z;
            o.w = acc2[i*4+3] + bv.w;
            *(float4*)&Vp[(size_t)row*DDIM + f0] = o;
        }
    }

    // fused histogram tail: grid-stride over edges
    const int stride = gridDim.x * 256;
    for (int e = blockIdx.x * 256 + tid; e < NE; e += stride)
        atomicAdd(&degi[dst[e]], 1);
}

// ---------------- split-bf16 weight fragment precompute ----------------
// Layout: WF[L][t][ks][hl][lane][j] shorts; per-layer stride 8192 shorts.
// lane: n=lane&15 (feature col), kg=lane>>4; f=t*16+n; k=ks*32+kg*8+j.
__global__ __launch_bounds__(256)
void prep_w_kernel(const float* __restrict__ W1, const float* __restrict__ W2,
                   const float* __restrict__ WB, const float* __restrict__ WC,
                   short* __restrict__ WF)
{
    int gid = blockIdx.x * 256 + threadIdx.x;   // grid = 64 blocks -> 16384 threads
    int L = gid >> 12, r = gid & 4095;
    int t = r >> 10, ks = (r >> 9) & 1, lane = (r >> 3) & 63, j = r & 7;
    const float* Ws = (L == 0) ? W1 : (L == 1) ? W2 : (L == 2) ? WB : WC;
    int n = lane & 15, kg = lane >> 4;
    int f = t*16 + n, k = ks*32 + kg*8 + j;
    float v = Ws[f*64 + k];
    unsigned short h = bf16_rn(v);
    unsigned short l = bf16_rn(v - bf16_tof(h));
    int base = L*8192 + ((t*2 + ks)*2)*512 + lane*8 + j;
    WF[base]       = (short)h;
    WF[base + 512] = (short)l;
}

// ---------------- CSR build: scan / scatter ----------------
__global__ __launch_bounds__(256)
void scan1_kernel(const int* __restrict__ degi, int* __restrict__ linc, int* __restrict__ bsum)
{
    __shared__ int ws[4];
    const int tid = threadIdx.x;
    const int lane = tid & 63, wv = tid >> 6;
    int i = blockIdx.x * 256 + tid;
    int v = (i < NN) ? degi[i] : 0;
    int sc = v;
    #pragma unroll
    for (int off = 1; off < 64; off <<= 1) {
        int t = __shfl_up(sc, off, 64);
        if (lane >= off) sc += t;
    }
    if (lane == 63) ws[wv] = sc;
    __syncthreads();
    int wb = 0;
    #pragma unroll
    for (int w = 0; w < 4; ++w) if (w < wv) wb += ws[w];
    int incl = sc + wb;
    if (i < NN) linc[i] = incl;
    if (tid == 255) bsum[blockIdx.x] = incl;
}

// merged scan2+scan3: each block re-scans the 196 block sums, picks its base,
// writes curs[i] = bbase + linc[i] - degi[i]
__global__ __launch_bounds__(256)
void scan23_kernel(const int* __restrict__ degi, const int* __restrict__ linc,
                   const int* __restrict__ bsum, int* __restrict__ curs)
{
    __shared__ int ws[4];
    __shared__ int base_s;
    const int tid = threadIdx.x;
    const int lane = tid & 63, wv = tid >> 6;
    int v = (tid < NB_SCAN) ? bsum[tid] : 0;
    int sc = v;
    #pragma unroll
    for (int off = 1; off < 64; off <<= 1) {
        int t = __shfl_up(sc, off, 64);
        if (lane >= off) sc += t;
    }
    if (lane == 63) ws[wv] = sc;
    __syncthreads();
    int wb = 0;
    #pragma unroll
    for (int w = 0; w < 4; ++w) if (w < wv) wb += ws[w];
    if (tid == blockIdx.x) base_s = sc + wb - v;   // exclusive prefix at blockIdx
    __syncthreads();
    int i = blockIdx.x * 256 + tid;
    if (i < NN) curs[i] = base_s + linc[i] - degi[i];
}

__global__ __launch_bounds__(256)
void scatter_kernel(const int* __restrict__ dst, int* __restrict__ cursor, int* __restrict__ eidx)
{
    int e = blockIdx.x * 256 + threadIdx.x;
    if (e < NE) {
        int p = atomicAdd(&cursor[dst[e]], 1);
        eidx[p] = e;
    }
}

// ---------------- split-bf16 MFMA edge kernel (W from global frags) ----------------
struct WFrags { bf16x8 bh[4][2]; bf16x8 bl[4][2]; };

__device__ __forceinline__ void load_wfrags(const short* __restrict__ WL, int lane, WFrags& w)
{
    #pragma unroll
    for (int t = 0; t < 4; ++t)
        #pragma unroll
        for (int ks = 0; ks < 2; ++ks) {
            w.bh[t][ks] = *(const bf16x8*)&WL[(((t*2 + ks)*2 + 0)*64 + lane)*8];
            w.bl[t][ks] = *(const bf16x8*)&WL[(((t*2 + ks)*2 + 1)*64 + lane)*8];
        }
}

__device__ __forceinline__ void mfma_gemm_r(const short* __restrict__ Xh, const short* __restrict__ Xl,
                                            const WFrags& w, int wv, int lane, f32x4 acc[4])
{
    const int m = lane & 15, kg = lane >> 4;
    const int arow = (wv*16 + m)*PADK + kg*8;
    bf16x8 ah0 = *(const bf16x8*)&Xh[arow];
    bf16x8 al0 = *(const bf16x8*)&Xl[arow];
    bf16x8 ah1 = *(const bf16x8*)&Xh[arow + 32];
    bf16x8 al1 = *(const bf16x8*)&Xl[arow + 32];
    #pragma unroll
    for (int t = 0; t < 4; ++t) {
        acc[t] = __builtin_amdgcn_mfma_f32_16x16x32_bf16(al0, w.bh[t][0], acc[t], 0, 0, 0);
        acc[t] = __builtin_amdgcn_mfma_f32_16x16x32_bf16(ah0, w.bl[t][0], acc[t], 0, 0, 0);
        acc[t] = __builtin_amdgcn_mfma_f32_16x16x32_bf16(ah0, w.bh[t][0], acc[t], 0, 0, 0);
        acc[t] = __builtin_amdgcn_mfma_f32_16x16x32_bf16(al1, w.bh[t][1], acc[t], 0, 0, 0);
        acc[t] = __builtin_amdgcn_mfma_f32_16x16x32_bf16(ah1, w.bl[t][1], acc[t], 0, 0, 0);
        acc[t] = __builtin_amdgcn_mfma_f32_16x16x32_bf16(ah1, w.bh[t][1], acc[t], 0, 0, 0);
    }
}

// D-layout (col=lane&15 -> feature, row=(lane>>4)*4+reg -> edge) + bias + relu
// -> back into Xh/Xl as next layer's A operand (X[e][f])
__device__ __forceinline__ void repack_relu(short* __restrict__ Xh, short* __restrict__ Xl,
                                            const f32x4 acc[4], const float* __restrict__ bias,
                                            int wv, int lane)
{
    const int n = lane & 15, mg = lane >> 4;
    #pragma unroll
    for (int t = 0; t < 4; ++t) {
        float b = bias[t*16 + n];
        #pragma unroll
        for (int r = 0; r < 4; ++r) {
            float y = fmaxf(acc[t][r] + b, 0.0f);
            int e = wv*16 + mg*4 + r;
            unsigned short h = bf16_rn(y);
            float lof = y - bf16_tof(h);
            Xh[e*PADK + t*16 + n] = (short)h;
            Xl[e*PADK + t*16 + n] = (short)bf16_rn(lof);
        }
    }
}

__global__ __launch_bounds__(256, 3)
void edge_kernel(const float* __restrict__ Eg,
                 const int* __restrict__ src, const int* __restrict__ dst,
                 const int* __restrict__ eidx,
                 const short* __restrict__ WF,
                 const float* __restrict__ b1, const float* __restrict__ b2,
                 const float* __restrict__ bB, const float* __restrict__ bC,
                 const float* __restrict__ Vp,
                 float* __restrict__ S1, float* __restrict__ S2)
{
    __shared__ __align__(16) char smem[2 * 64 * PADK * 2];   // 18432 B: Xh/Xl, aliased by M1T
    __shared__ int srcs[64], dsts[64];
    short* Xh = (short*)smem;
    short* Xl = Xh + 64*PADK;
    float* M1T = (float*)smem;            // [f][e] stride PADM (17664 B < 18432)

    const int tid = threadIdx.x;
    const int lane = tid & 63, wv = tid >> 6;
    const int eb = blockIdx.x * 64;       // NE == 12500*64 exactly

    // stage E tile (dst-sorted permutation) as hi/lo bf16 X[e][k]
    #pragma unroll
    for (int c = 0; c < 4; ++c) {
        int idx = (c << 10) + (tid << 2);
        int e = idx >> 6, d = idx & 63;
        int eg = eidx[eb + e];
        float4 v = *(const float4*)&Eg[(size_t)eg*DDIM + d];
        ushort4 h, l;
        h.x = bf16_rn(v.x); l.x = bf16_rn(v.x - bf16_tof(h.x));
        h.y = bf16_rn(v.y); l.y = bf16_rn(v.y - bf16_tof(h.y));
        h.z = bf16_rn(v.z); l.z = bf16_rn(v.z - bf16_tof(h.z));
        h.w = bf16_rn(v.w); l.w = bf16_rn(v.w - bf16_tof(h.w));
        *(ushort4*)&Xh[e*PADK + d] = h;
        *(ushort4*)&Xl[e*PADK + d] = l;
    }
    if (tid < 64) {
        int eg = eidx[eb + tid];
        srcs[tid] = src[eg];
        dsts[tid] = dst[eg];
    }
    WFrags w;
    load_wfrags(WF, lane, w);             // layer 1 W, overlaps E staging
    __syncthreads();

    // layer 1
    f32x4 acc[4];
    #pragma unroll
    for (int t = 0; t < 4; ++t) acc[t] = (f32x4){0.f, 0.f, 0.f, 0.f};
    mfma_gemm_r(Xh, Xl, w, wv, lane, acc);
    __syncthreads();                       // all X reads done
    repack_relu(Xh, Xl, acc, b1, wv, lane);
    load_wfrags(WF + 8192, lane, w);       // layer 2 W
    __syncthreads();

    // layer 2
    #pragma unroll
    for (int t = 0; t < 4; ++t) acc[t] = (f32x4){0.f, 0.f, 0.f, 0.f};
    mfma_gemm_r(Xh, Xl, w, wv, lane, acc);
    __syncthreads();
    repack_relu(Xh, Xl, acc, b2, wv, lane);   // X = x2
    load_wfrags(WF + 2*8192, lane, w);        // scale head W
    __syncthreads();

    // scale + shift heads (both read same X, no barrier between)
    f32x4 accS[4], accH[4];
    #pragma unroll
    for (int t = 0; t < 4; ++t) { accS[t] = (f32x4){0.f,0.f,0.f,0.f}; accH[t] = (f32x4){0.f,0.f,0.f,0.f}; }
    mfma_gemm_r(Xh, Xl, w, wv, lane, accS);
    load_wfrags(WF + 3*8192, lane, w);        // shift head W
    mfma_gemm_r(Xh, Xl, w, wv, lane, accH);
    __syncthreads();                          // X reads done — M1T may alias

    // message phase in D-layout registers: lane owns f = t*16+n, e = wv*16+mg*4+r
    {
        const int n = lane & 15, mg = lane >> 4;
        int sn[4];
        #pragma unroll
        for (int r = 0; r < 4; ++r) sn[r] = srcs[wv*16 + mg*4 + r];
        #pragma unroll
        for (int t = 0; t < 4; ++t) {
            const int f = t*16 + n;
            const float bBv = bB[f];
            const float bCv = bC[f];
            #pragma unroll
            for (int r = 0; r < 4; ++r) {
                float vp = Vp[(size_t)sn[r]*DDIM + f];
                float sg = 1.0f / (1.0f + __expf(-(accS[t][r] + bBv)));
                float m1 = fmaf(sg, vp, accH[t][r] + bCv);
                M1T[f*PADM + wv*16 + mg*4 + r] = m1;
            }
        }
    }
    __syncthreads();

    // segmented reduction: thread = (feature f, 16-edge group g); edges sorted by dst
    const int f = tid >> 2;
    const int g = (tid & 3) << 4;
    float s1 = 0.f, s2 = 0.f;
    int prev = dsts[g];
    #pragma unroll 4
    for (int i = 0; i < 16; ++i) {
        int dn = dsts[g + i];
        float m1 = M1T[f*PADM + g + i];
        float m2 = m1 * m1;
        if (dn != prev) {
            atomicAdd(&S1[(size_t)prev*DDIM + f], s1);
            atomicAdd(&S2[(size_t)prev*DDIM + f], s2);
            s1 = 0.f; s2 = 0.f; prev = dn;
        }
        s1 += m1; s2 += m2;
    }
    atomicAdd(&S1[(size_t)prev*DDIM + f], s1);
    atomicAdd(&S2[(size_t)prev*DDIM + f], s2);
}

// ---------------- finalize ----------------
__global__ __launch_bounds__(256)
void finalize_kernel(const float* __restrict__ S1, const float* __restrict__ S2,
                     const int* __restrict__ degi, float* __restrict__ out)
{
    int gid = blockIdx.x * blockDim.x + threadIdx.x;
    if (gid >= NN*DDIM) return;
    int n = gid >> 6;
    float dn = (float)degi[n];
    dn = dn > 1.0f ? dn : 1.0f;
    float v = (S2[gid] - S1[gid]) / dn;
    out[gid] = sqrtf(fmaxf(v, 0.0f) + EPS_V);
}

extern "C" void kernel_launch(void* const* d_in, const int* in_sizes, int n_in,
                              void* d_out, int out_size, void* d_ws, size_t ws_size,
                              hipStream_t stream) {
    const float* V   = (const float*)d_in[0];
    const float* Eg  = (const float*)d_in[1];
    const int*   src = (const int*)d_in[2];
    const int*   dst = (const int*)d_in[3];
    const float* pAw = (const float*)d_in[4];
    const float* pAb = (const float*)d_in[5];
    const float* pBw = (const float*)d_in[6];
    const float* pBb = (const float*)d_in[7];
    const float* mW1 = (const float*)d_in[8];
    const float* mb1 = (const float*)d_in[9];
    const float* mW2 = (const float*)d_in[10];
    const float* mb2 = (const float*)d_in[11];
    const float* BW  = (const float*)d_in[12];
    const float* Bb  = (const float*)d_in[13];
    const float* CW  = (const float*)d_in[14];
    const float* Cb  = (const float*)d_in[15];
    float* out = (float*)d_out;

    float* ws    = (float*)d_ws;
    float* Vp    = ws;                                   // NN*DDIM f32
    float* S1    = ws + (size_t)NN*DDIM;                 // NN*DDIM f32
    float* S2    = ws + (size_t)2*NN*DDIM;               // NN*DDIM f32
    int*   degi  = (int*)(ws + (size_t)3*NN*DDIM);       // NN i32
    int*   curs  = degi + NN;                            // NN i32
    int*   linc  = curs + NN;                            // NN i32
    int*   bsum  = linc + NN;                            // NB_SCAN i32
    int*   bbase = bsum + NB_SCAN;                       // NB_SCAN i32 (unused, keeps layout)
    int*   eidx  = bbase + NB_SCAN;                      // NE i32
    short* WF    = (short*)(eidx + NE);                  // 4*8192 shorts (64 KB)

    // zero S1, S2, degi (contiguous)
    hipMemsetAsync(S1, 0, (size_t)(2*NN*DDIM + NN) * sizeof(float), stream);

    prep_w_kernel<<<64, 256, 0, stream>>>(mW1, mW2, BW, CW, WF);
    node_pool_kernel<<<(NN + 63)/64, 256, 0, stream>>>(V, pAw, pAb, pBw, pBb, Vp, dst, degi);
    scan1_kernel<<<NB_SCAN, 256, 0, stream>>>(degi, linc, bsum);
    scan23_kernel<<<NB_SCAN, 256, 0, stream>>>(degi, linc, bsum, curs);
    scatter_kernel<<<(NE + 255)/256, 256, 0, stream>>>(dst, curs, eidx);
    edge_kernel<<<NE/64, 256, 0, stream>>>(Eg, src, dst, eidx, WF,
                                           mb1, mb2, Bb, Cb, Vp, S1, S2);
    finalize_kernel<<<(NN*DDIM + 255)/256, 256, 0, stream>>>(S1, S2, degi, out);
}

// Round 5
// 581.481 us; speedup vs baseline: 2.8599x; 1.0050x over previous
//
#include <hip/hip_runtime.h>

#define NN 50000
#define NE 800000
#define DDIM 64
#define PADX 68          // fp32 LDS row stride (node pool)
#define PADS 68          // fp32 per-wave scratch stride (rows are 272 B -> 16B aligned, odd*4 banks)
#define NB_SCAN ((NN + 255) / 256)   // 196
#define NEG_SLOPE 0.2f
#define EPS_V 1e-5f

typedef short bf16x8 __attribute__((ext_vector_type(8)));
typedef float f32x4 __attribute__((ext_vector_type(4)));

__device__ __forceinline__ float lrelu_f(float x) { return x >= 0.0f ? x : NEG_SLOPE * x; }

__device__ __forceinline__ unsigned short bf16_rn(float x) {
    union { float f; unsigned int u; } c; c.f = x;
    unsigned int r = c.u + 0x7FFF + ((c.u >> 16) & 1);
    return (unsigned short)(r >> 16);
}
__device__ __forceinline__ float bf16_tof(unsigned short h) {
    union { float f; unsigned int u; } c; c.u = ((unsigned int)h) << 16;
    return c.f;
}

// split 8 fp32 -> hi/lo bf16x8 (round-to-nearest both; ~2^-18 effective rel err)
__device__ __forceinline__ void split8(const float* __restrict__ v, bf16x8& h, bf16x8& l)
{
    #pragma unroll
    for (int j = 0; j < 8; ++j) {
        unsigned short hh = bf16_rn(v[j]);
        h[j] = (short)hh;
        l[j] = (short)bf16_rn(v[j] - bf16_tof(hh));
    }
}

// ---------------- fp32 micro-tile GEMM helpers (node pooling only) ----------------
__device__ __forceinline__ void mma_tile(float acc[16], const float* __restrict__ XT,
                                         const float* __restrict__ Wc, int e0, int f0)
{
    #pragma unroll 4
    for (int kk = 0; kk < DDIM; kk += 4) {
        float4 A0 = *(const float4*)&XT[(kk+0)*PADX + e0];
        float4 A1 = *(const float4*)&XT[(kk+1)*PADX + e0];
        float4 A2 = *(const float4*)&XT[(kk+2)*PADX + e0];
        float4 A3 = *(const float4*)&XT[(kk+3)*PADX + e0];
        float4 B0 = *(const float4*)&Wc[(f0+0)*PADX + kk];
        float4 B1 = *(const float4*)&Wc[(f0+1)*PADX + kk];
        float4 B2 = *(const float4*)&Wc[(f0+2)*PADX + kk];
        float4 B3 = *(const float4*)&Wc[(f0+3)*PADX + kk];
        const float a[4][4] = {{A0.x,A0.y,A0.z,A0.w},{A1.x,A1.y,A1.z,A1.w},
                               {A2.x,A2.y,A2.z,A2.w},{A3.x,A3.y,A3.z,A3.w}};
        const float b[4][4] = {{B0.x,B0.y,B0.z,B0.w},{B1.x,B1.y,B1.z,B1.w},
                               {B2.x,B2.y,B2.z,B2.w},{B3.x,B3.y,B3.z,B3.w}};
        #pragma unroll
        for (int j = 0; j < 4; ++j)
            #pragma unroll
            for (int i = 0; i < 4; ++i)
                #pragma unroll
                for (int q = 0; q < 4; ++q)
                    acc[i*4+j] = fmaf(a[q][i], b[j][q], acc[i*4+j]);
    }
}

__device__ __forceinline__ void load_w_f32(float* __restrict__ Wc, const float* __restrict__ Wg, int tid)
{
    #pragma unroll
    for (int c = 0; c < 4; ++c) {
        int idx = (c << 10) + (tid << 2);
        int f = idx >> 6, k = idx & 63;
        *(float4*)&Wc[f*PADX + k] = *(const float4*)&Wg[idx];
    }
}

// ---------------- node pooling (fp32) + fused dst histogram ----------------
__global__ __launch_bounds__(256, 3)
void node_pool_kernel(const float* __restrict__ V,
                      const float* __restrict__ Aw, const float* __restrict__ Ab,
                      const float* __restrict__ Bw, const float* __restrict__ Bbv,
                      float* __restrict__ Vp,
                      const int* __restrict__ dst, int* __restrict__ degi)
{
    __shared__ float Wc[DDIM*PADX];
    __shared__ float XT[DDIM*PADX];
    const int tid = threadIdx.x;
    const int nb = blockIdx.x * 64;
    const int e0 = (tid & 15) << 2;
    const int f0 = (tid >> 4) << 2;

    #pragma unroll
    for (int c = 0; c < 4; ++c) {
        int idx = (c << 10) + (tid << 2);
        int e = idx >> 6, d = idx & 63;
        int row = nb + e; if (row > NN-1) row = NN-1;
        float4 v = *(const float4*)&V[(size_t)row*DDIM + d];
        XT[(d+0)*PADX + e] = lrelu_f(v.x);
        XT[(d+1)*PADX + e] = lrelu_f(v.y);
        XT[(d+2)*PADX + e] = lrelu_f(v.z);
        XT[(d+3)*PADX + e] = lrelu_f(v.w);
    }
    load_w_f32(Wc, Aw, tid);
    __syncthreads();

    float acc[16];
    #pragma unroll
    for (int i = 0; i < 16; ++i) acc[i] = 0.f;
    mma_tile(acc, XT, Wc, e0, f0);
    __syncthreads();

    {   // lrelu(acc + Ab) -> XT
        float4 bv = *(const float4*)&Ab[f0];
        const float ba[4] = {bv.x, bv.y, bv.z, bv.w};
        #pragma unroll
        for (int j = 0; j < 4; ++j) {
            float4 v;
            v.x = lrelu_f(acc[0*4+j] + ba[j]);
            v.y = lrelu_f(acc[1*4+j] + ba[j]);
            v.z = lrelu_f(acc[2*4+j] + ba[j]);
            v.w = lrelu_f(acc[3*4+j] + ba[j]);
            *(float4*)&XT[(f0+j)*PADX + e0] = v;
        }
    }
    load_w_f32(Wc, Bw, tid);
    __syncthreads();

    float acc2[16];
    #pragma unroll
    for (int i = 0; i < 16; ++i) acc2[i] = 0.f;
    mma_tile(acc2, XT, Wc, e0, f0);

    float4 bv = *(const float4*)&Bbv[f0];
    #pragma unroll
    for (int i = 0; i < 4; ++i) {
        int row = nb + e0 + i;
        if (row < NN) {
            float4 o;
            o.x = acc2[i*4+0] + bv.x;
            o.y = acc2[i*4+1] + bv.y;
            o.z = acc2[i*4+2] + bv.z;
            o.w = acc2[i*4+3] + bv.w;
            *(float4*)&Vp[(size_t)row*DDIM + f0] = o;
        }
    }

    // fused histogram tail: grid-stride over edges
    const int stride = gridDim.x * 256;
    for (int e = blockIdx.x * 256 + tid; e < NE; e += stride)
        atomicAdd(&degi[dst[e]], 1);
}

// ---------------- split-bf16 weight fragment precompute ----------------
// Layout: WF[L][t][ks][hl][lane][j] shorts; per-layer stride 8192 shorts.
// lane: n=lane&15 (feature col), kg=lane>>4; f=t*16+n; k=ks*32+kg*8+j.
__global__ __launch_bounds__(256)
void prep_w_kernel(const float* __restrict__ W1, const float* __restrict__ W2,
                   const float* __restrict__ WB, const float* __restrict__ WC,
                   short* __restrict__ WF)
{
    int gid = blockIdx.x * 256 + threadIdx.x;   // grid = 64 blocks -> 16384 threads
    int L = gid >> 12, r = gid & 4095;
    int t = r >> 10, ks = (r >> 9) & 1, lane = (r >> 3) & 63, j = r & 7;
    const float* Ws = (L == 0) ? W1 : (L == 1) ? W2 : (L == 2) ? WB : WC;
    int n = lane & 15, kg = lane >> 4;
    int f = t*16 + n, k = ks*32 + kg*8 + j;
    float v = Ws[f*64 + k];
    unsigned short h = bf16_rn(v);
    unsigned short l = bf16_rn(v - bf16_tof(h));
    int base = L*8192 + ((t*2 + ks)*2)*512 + lane*8 + j;
    WF[base]       = (short)h;
    WF[base + 512] = (short)l;
}

// ---------------- CSR build: scan / scatter ----------------
__global__ __launch_bounds__(256)
void scan1_kernel(const int* __restrict__ degi, int* __restrict__ linc, int* __restrict__ bsum)
{
    __shared__ int ws[4];
    const int tid = threadIdx.x;
    const int lane = tid & 63, wv = tid >> 6;
    int i = blockIdx.x * 256 + tid;
    int v = (i < NN) ? degi[i] : 0;
    int sc = v;
    #pragma unroll
    for (int off = 1; off < 64; off <<= 1) {
        int t = __shfl_up(sc, off, 64);
        if (lane >= off) sc += t;
    }
    if (lane == 63) ws[wv] = sc;
    __syncthreads();
    int wb = 0;
    #pragma unroll
    for (int w = 0; w < 4; ++w) if (w < wv) wb += ws[w];
    int incl = sc + wb;
    if (i < NN) linc[i] = incl;
    if (tid == 255) bsum[blockIdx.x] = incl;
}

__global__ __launch_bounds__(256)
void scan23_kernel(const int* __restrict__ degi, const int* __restrict__ linc,
                   const int* __restrict__ bsum, int* __restrict__ curs)
{
    __shared__ int ws[4];
    __shared__ int base_s;
    const int tid = threadIdx.x;
    const int lane = tid & 63, wv = tid >> 6;
    int v = (tid < NB_SCAN) ? bsum[tid] : 0;
    int sc = v;
    #pragma unroll
    for (int off = 1; off < 64; off <<= 1) {
        int t = __shfl_up(sc, off, 64);
        if (lane >= off) sc += t;
    }
    if (lane == 63) ws[wv] = sc;
    __syncthreads();
    int wb = 0;
    #pragma unroll
    for (int w = 0; w < 4; ++w) if (w < wv) wb += ws[w];
    if (tid == blockIdx.x) base_s = sc + wb - v;
    __syncthreads();
    int i = blockIdx.x * 256 + tid;
    if (i < NN) curs[i] = base_s + linc[i] - degi[i];
}

__global__ __launch_bounds__(256)
void scatter_kernel(const int* __restrict__ dst, int* __restrict__ cursor, int* __restrict__ eidx)
{
    int e = blockIdx.x * 256 + threadIdx.x;
    if (e < NE) {
        int p = atomicAdd(&cursor[dst[e]], 1);
        eidx[p] = e;
    }
}

// ---------------- barrier-free per-wave split-bf16 MFMA edge kernel ----------------
// per-ks W fragment load: 8 frags (32 VGPRs)
__device__ __forceinline__ void gemm64(const short* __restrict__ WL, int lane,
                                       const bf16x8 ah[2], const bf16x8 al[2], f32x4 acc[4])
{
    #pragma unroll
    for (int ks = 0; ks < 2; ++ks) {
        bf16x8 bh[4], bl[4];
        #pragma unroll
        for (int t = 0; t < 4; ++t) {
            bh[t] = *(const bf16x8*)&WL[(((t*2 + ks)*2 + 0)*64 + lane)*8];
            bl[t] = *(const bf16x8*)&WL[(((t*2 + ks)*2 + 1)*64 + lane)*8];
        }
        #pragma unroll
        for (int t = 0; t < 4; ++t) {
            acc[t] = __builtin_amdgcn_mfma_f32_16x16x32_bf16(al[ks], bh[t], acc[t], 0, 0, 0);
            acc[t] = __builtin_amdgcn_mfma_f32_16x16x32_bf16(ah[ks], bl[t], acc[t], 0, 0, 0);
            acc[t] = __builtin_amdgcn_mfma_f32_16x16x32_bf16(ah[ks], bh[t], acc[t], 0, 0, 0);
        }
    }
}

// D-layout y[t][r] (f=t*16+n, e=mg*4+r) -> per-wave LDS -> A-frags for next layer.
// Wave-lockstep: DS ops from one wave complete in order; no __syncthreads needed.
__device__ __forceinline__ void transpose_frags(float* __restrict__ sw, const f32x4 y[4],
                                                int lane, bf16x8 ah[2], bf16x8 al[2])
{
    const int n = lane & 15, mg = lane >> 4;
    #pragma unroll
    for (int t = 0; t < 4; ++t)
        #pragma unroll
        for (int r = 0; r < 4; ++r)
            sw[(mg*4 + r)*PADS + t*16 + n] = y[t][r];
    __builtin_amdgcn_wave_barrier();
    const int m = lane & 15, kg = lane >> 4;   // m: edge row, kg: k-group
    float x[16];
    *(float4*)&x[0]  = *(const float4*)&sw[m*PADS + kg*8];
    *(float4*)&x[4]  = *(const float4*)&sw[m*PADS + kg*8 + 4];
    *(float4*)&x[8]  = *(const float4*)&sw[m*PADS + 32 + kg*8];
    *(float4*)&x[12] = *(const float4*)&sw[m*PADS + 32 + kg*8 + 4];
    split8(&x[0], ah[0], al[0]);
    split8(&x[8], ah[1], al[1]);
    __builtin_amdgcn_wave_barrier();
}

__global__ __launch_bounds__(256, 4)
void edge_kernel(const float* __restrict__ Eg,
                 const int* __restrict__ src, const int* __restrict__ dst,
                 const int* __restrict__ eidx,
                 const short* __restrict__ WF,
                 const float* __restrict__ b1, const float* __restrict__ b2,
                 const float* __restrict__ bB, const float* __restrict__ bC,
                 const float* __restrict__ Vp,
                 float* __restrict__ S1, float* __restrict__ S2)
{
    __shared__ float scratch[4 * 16 * PADS];   // per-wave 16x68 fp32 tiles (17408 B)
    __shared__ int aux[4 * 32];                // per-wave: [0..15]=src, [16..31]=dst

    const int tid = threadIdx.x;
    const int lane = tid & 63, wv = tid >> 6;
    float* sw = scratch + wv * 16 * PADS;
    int* auxw = aux + wv * 32;

    const int ew = blockIdx.x * 64 + wv * 16;  // this wave's 16 edges (dst-sorted)
    const int m = lane & 15, kg = lane >> 4;

    // stage: indices + E rows straight into A-fragments (no LDS)
    int eg = eidx[ew + m];
    if (lane < 16) {
        auxw[lane]      = src[eg];
        auxw[16 + lane] = dst[eg];
    }
    bf16x8 ah[2], al[2];
    {
        const float* er = Eg + (size_t)eg*DDIM + kg*8;
        float x[16];
        *(float4*)&x[0]  = *(const float4*)&er[0];
        *(float4*)&x[4]  = *(const float4*)&er[4];
        *(float4*)&x[8]  = *(const float4*)&er[32];
        *(float4*)&x[12] = *(const float4*)&er[36];
        split8(&x[0], ah[0], al[0]);
        split8(&x[8], ah[1], al[1]);
    }

    const int n = lane & 15, mg = lane >> 4;

    // layer 1
    f32x4 acc[4];
    #pragma unroll
    for (int t = 0; t < 4; ++t) acc[t] = (f32x4){0.f, 0.f, 0.f, 0.f};
    gemm64(WF, lane, ah, al, acc);
    #pragma unroll
    for (int t = 0; t < 4; ++t) {
        float b = b1[t*16 + n];
        #pragma unroll
        for (int r = 0; r < 4; ++r) acc[t][r] = fmaxf(acc[t][r] + b, 0.0f);
    }
    transpose_frags(sw, acc, lane, ah, al);

    // layer 2
    #pragma unroll
    for (int t = 0; t < 4; ++t) acc[t] = (f32x4){0.f, 0.f, 0.f, 0.f};
    gemm64(WF + 8192, lane, ah, al, acc);
    #pragma unroll
    for (int t = 0; t < 4; ++t) {
        float b = b2[t*16 + n];
        #pragma unroll
        for (int r = 0; r < 4; ++r) acc[t][r] = fmaxf(acc[t][r] + b, 0.0f);
    }
    transpose_frags(sw, acc, lane, ah, al);    // a-frags = x2

    // scale + shift heads (same A operand)
    f32x4 accS[4], accH[4];
    #pragma unroll
    for (int t = 0; t < 4; ++t) { accS[t] = (f32x4){0.f,0.f,0.f,0.f}; accH[t] = (f32x4){0.f,0.f,0.f,0.f}; }
    gemm64(WF + 2*8192, lane, ah, al, accS);
    gemm64(WF + 3*8192, lane, ah, al, accH);

    // message phase in D-layout registers: lane owns f=t*16+n, local edge e=mg*4+r
    {
        int sn[4];
        #pragma unroll
        for (int r = 0; r < 4; ++r) sn[r] = auxw[mg*4 + r];
        #pragma unroll
        for (int t = 0; t < 4; ++t) {
            const int f = t*16 + n;
            const float bBv = bB[f];
            const float bCv = bC[f];
            #pragma unroll
            for (int r = 0; r < 4; ++r) {
                float vp = Vp[(size_t)sn[r]*DDIM + f];
                float sg = 1.0f / (1.0f + __expf(-(accS[t][r] + bBv)));
                float m1 = fmaf(sg, vp, accH[t][r] + bCv);
                sw[(mg*4 + r)*PADS + f] = m1;
            }
        }
    }
    __builtin_amdgcn_wave_barrier();

    // per-wave segmented reduction: lane = feature (0..63), 16 dst-sorted edges
    const int f = lane;
    float s1 = 0.f, s2 = 0.f;
    int prev = auxw[16];
    #pragma unroll 4
    for (int e = 0; e < 16; ++e) {
        int dn = auxw[16 + e];
        float m1 = sw[e*PADS + f];
        float m2 = m1 * m1;
        if (dn != prev) {
            atomicAdd(&S1[(size_t)prev*DDIM + f], s1);
            atomicAdd(&S2[(size_t)prev*DDIM + f], s2);
            s1 = 0.f; s2 = 0.f; prev = dn;
        }
        s1 += m1; s2 += m2;
    }
    atomicAdd(&S1[(size_t)prev*DDIM + f], s1);
    atomicAdd(&S2[(size_t)prev*DDIM + f], s2);
}

// ---------------- finalize ----------------
__global__ __launch_bounds__(256)
void finalize_kernel(const float* __restrict__ S1, const float* __restrict__ S2,
                     const int* __restrict__ degi, float* __restrict__ out)
{
    int gid = blockIdx.x * blockDim.x + threadIdx.x;
    if (gid >= NN*DDIM) return;
    int n = gid >> 6;
    float dn = (float)degi[n];
    dn = dn > 1.0f ? dn : 1.0f;
    float v = (S2[gid] - S1[gid]) / dn;
    out[gid] = sqrtf(fmaxf(v, 0.0f) + EPS_V);
}

extern "C" void kernel_launch(void* const* d_in, const int* in_sizes, int n_in,
                              void* d_out, int out_size, void* d_ws, size_t ws_size,
                              hipStream_t stream) {
    const float* V   = (const float*)d_in[0];
    const float* Eg  = (const float*)d_in[1];
    const int*   src = (const int*)d_in[2];
    const int*   dst = (const int*)d_in[3];
    const float* pAw = (const float*)d_in[4];
    const float* pAb = (const float*)d_in[5];
    const float* pBw = (const float*)d_in[6];
    const float* pBb = (const float*)d_in[7];
    const float* mW1 = (const float*)d_in[8];
    const float* mb1 = (const float*)d_in[9];
    const float* mW2 = (const float*)d_in[10];
    const float* mb2 = (const float*)d_in[11];
    const float* BW  = (const float*)d_in[12];
    const float* Bb  = (const float*)d_in[13];
    const float* CW  = (const float*)d_in[14];
    const float* Cb  = (const float*)d_in[15];
    float* out = (float*)d_out;

    float* ws    = (float*)d_ws;
    float* Vp    = ws;                                   // NN*DDIM f32
    float* S1    = ws + (size_t)NN*DDIM;                 // NN*DDIM f32
    float* S2    = ws + (size_t)2*NN*DDIM;               // NN*DDIM f32
    int*   degi  = (int*)(ws + (size_t)3*NN*DDIM);       // NN i32
    int*   curs  = degi + NN;                            // NN i32
    int*   linc  = curs + NN;                            // NN i32
    int*   bsum  = linc + NN;                            // NB_SCAN i32
    int*   bbase = bsum + NB_SCAN;                       // NB_SCAN i32 (layout keep)
    int*   eidx  = bbase + NB_SCAN;                      // NE i32
    short* WF    = (short*)(eidx + NE);                  // 4*8192 shorts (64 KB)

    hipMemsetAsync(S1, 0, (size_t)(2*NN*DDIM + NN) * sizeof(float), stream);

    prep_w_kernel<<<64, 256, 0, stream>>>(mW1, mW2, BW, CW, WF);
    node_pool_kernel<<<(NN + 63)/64, 256, 0, stream>>>(V, pAw, pAb, pBw, pBb, Vp, dst, degi);
    scan1_kernel<<<NB_SCAN, 256, 0, stream>>>(degi, linc, bsum);
    scan23_kernel<<<NB_SCAN, 256, 0, stream>>>(degi, linc, bsum, curs);
    scatter_kernel<<<(NE + 255)/256, 256, 0, stream>>>(dst, curs, eidx);
    edge_kernel<<<NE/64, 256, 0, stream>>>(Eg, src, dst, eidx, WF,
                                           mb1, mb2, Bb, Cb, Vp, S1, S2);
    finalize_kernel<<<(NN*DDIM + 255)/256, 256, 0, stream>>>(S1, S2, degi, out);
}